// Round 14
// baseline (822.063 us; speedup 1.0000x reference)
//
#include <hip/hip_runtime.h>
#include <cstdint>
#include <cstddef>

#define NN 100000
#define NP 100032
#define NE 800000
#define NG 256
#define NL 5
#define EPS 1e-5f
#define NSTRIPE 32

typedef __bf16 bf16x8 __attribute__((ext_vector_type(8)));
typedef float f32x4 __attribute__((ext_vector_type(4)));

__device__ __forceinline__ float bf2f(unsigned short u) {
  union { unsigned int i; float f; } x; x.i = ((unsigned int)u) << 16; return x.f;
}
__device__ __forceinline__ unsigned short f2bf(float f) {
  union { float f; unsigned int i; } x; x.f = f;
  unsigned int r = x.i + 0x7fffu + ((x.i >> 16) & 1u);
  return (unsigned short)(r >> 16);
}

// ---------------- fused prep: A = bf16(atom_emb[x]) | weight transpose | cnt+dhist zero ----------------
__global__ __launch_bounds__(256) void prep_k(const int* __restrict__ x,
                                              const float* __restrict__ atom_emb,
                                              unsigned short* __restrict__ A,
                                              const float* __restrict__ W1,
                                              const float* __restrict__ W2,
                                              unsigned short* __restrict__ Wt1,
                                              unsigned short* __restrict__ Wt2,
                                              int* __restrict__ cnt) {
  int b = blockIdx.x, t = threadIdx.x;
  if (b < 3125) {                       // init h: NN*8 threads
    int i = b * 256 + t;
    int n = i >> 3, c0 = (i & 7) * 8;
    const float* p = atom_emb + (size_t)x[n] * 64 + c0;
    float4 v0 = *(const float4*)p;
    float4 v1 = *(const float4*)(p + 4);
    union { bf16x8 b8; unsigned short u[8]; } o;
    o.u[0] = f2bf(v0.x); o.u[1] = f2bf(v0.y); o.u[2] = f2bf(v0.z); o.u[3] = f2bf(v0.w);
    o.u[4] = f2bf(v1.x); o.u[5] = f2bf(v1.y); o.u[6] = f2bf(v1.z); o.u[7] = f2bf(v1.w);
    *(bf16x8*)(A + (size_t)n * 64 + c0) = o.b8;
  } else if (b < 3445) {                // wconv: 81920 threads (320 blocks exactly)
    int i = (b - 3125) * 256 + t;
    const int S = NL * 128 * 64;        // 40960
    if (i < S) {
      int l = i / (128 * 64), r = i % (128 * 64);
      int c = r / 64, k = r % 64;
      Wt1[i] = f2bf(W1[(size_t)l * 64 * 128 + (size_t)k * 128 + c]);
    } else {
      int j = i - S;
      int l = j / (128 * 64), r = j % (128 * 64);
      int c = r / 128, k = r % 128;
      Wt2[j] = f2bf(W2[(size_t)l * 128 * 64 + (size_t)k * 64 + c]);
    }
  } else {                              // zero cnt + dhist + dofs (NN+128 ints)
    int i = (b - 3445) * 256 + t;
    if (i < NN + 128) cnt[i] = 0;
  }
}

// ---------------- CSR build ----------------
__global__ __launch_bounds__(256) void hist_k(const int* __restrict__ ei,
                                              int* __restrict__ cnt) {
  int e = blockIdx.x * 256 + threadIdx.x;
  if (e >= NE) return;
  atomicAdd(&cnt[ei[NE + e]], 1);
}

// exclusive scan of cnt -> rs, block sums -> bsum; also degree histogram -> dhist
__global__ __launch_bounds__(256) void scan1_k(const int* __restrict__ cnt,
                                               int* __restrict__ rs,
                                               int* __restrict__ bsum,
                                               int* __restrict__ dhist) {
  __shared__ int sh[256];
  __shared__ int dh[64];
  int t = threadIdx.x;
  if (t < 64) dh[t] = 0;
  int base = blockIdx.x * 1024 + t * 4;
  int v0 = 0, v1 = 0, v2 = 0, v3 = 0;
  if (base + 0 < NN) v0 = cnt[base + 0];
  if (base + 1 < NN) v1 = cnt[base + 1];
  if (base + 2 < NN) v2 = cnt[base + 2];
  if (base + 3 < NN) v3 = cnt[base + 3];
  int tsum = v0 + v1 + v2 + v3;
  sh[t] = tsum;
  __syncthreads();
  if (base + 0 < NN) atomicAdd(&dh[v0 < 63 ? v0 : 63], 1);
  if (base + 1 < NN) atomicAdd(&dh[v1 < 63 ? v1 : 63], 1);
  if (base + 2 < NN) atomicAdd(&dh[v2 < 63 ? v2 : 63], 1);
  if (base + 3 < NN) atomicAdd(&dh[v3 < 63 ? v3 : 63], 1);
  for (int off = 1; off < 256; off <<= 1) {
    int x = (t >= off) ? sh[t - off] : 0;
    __syncthreads();
    sh[t] += x;
    __syncthreads();
  }
  int excl = sh[t] - tsum;
  if (base + 0 < NN) rs[base + 0] = excl;
  if (base + 1 < NN) rs[base + 1] = excl + v0;
  if (base + 2 < NN) rs[base + 2] = excl + v0 + v1;
  if (base + 3 < NN) rs[base + 3] = excl + v0 + v1 + v2;
  if (t == 255) bsum[blockIdx.x] = sh[255];
  __syncthreads();
  if (t < 64 && dh[t]) atomicAdd(&dhist[t], dh[t]);
}

// tiny: exclusive prefix of 64-entry degree histogram -> dofs
__global__ void dscan_k(const int* __restrict__ dhist, int* __restrict__ dofs) {
  if (threadIdx.x == 0 && blockIdx.x == 0) {
    int run = 0;
    for (int d = 0; d < 64; ++d) { dofs[d] = run; run += dhist[d]; }
  }
}

// scan3: fold block-sum prefix; init cursor; scatter degree-sorted perm
__global__ __launch_bounds__(256) void scan3_k(int* __restrict__ rs,
                                               const int* __restrict__ bsum,
                                               int* __restrict__ cursor,
                                               const int* __restrict__ cnt,
                                               int* __restrict__ dofs,
                                               int* __restrict__ perm) {
  int i = blockIdx.x * 256 + threadIdx.x;
  int chunk = blockIdx.x >> 2;
  int boff = 0;
  for (int j = 0; j < chunk; ++j) boff += bsum[j];
  if (i < NN) {
    int v = rs[i] + boff;
    rs[i] = v;
    cursor[i] = v;
    int d = cnt[i]; if (d > 63) d = 63;
    int slot = atomicAdd(&dofs[d], 1);
    perm[slot] = i;
  }
  if (i == 0) rs[NN] = NE;
}

// banded scatter: 4 bands of 25000 rows; each pass's epack slice stays cache-local
__global__ __launch_bounds__(256) void scatter_k(const int* __restrict__ ei,
                                                 const int* __restrict__ eattr,
                                                 int* __restrict__ cursor,
                                                 int* __restrict__ epack) {
  int band = blockIdx.x & 3;
  int e = (blockIdx.x >> 2) * 256 + threadIdx.x;
  if (e >= NE) return;
  int d = ei[NE + e];
  if (d / 25000 != band) return;
  int slot = atomicAdd(&cursor[d], 1);
  epack[slot] = (ei[e] << 3) | eattr[e];
}

// ---------------- gather + fused stat1 (degree-sorted rows) ----------------
// B[row] = hsrc(row) + sum relu(hsrc(src)+bond[b]); hsrc = MODE ? relu(A*scl+shf) : A.
// Subgroup-per-row (sg 0-7 = row, ch 0-7 = channels); row = perm[...]: rows in a wave
// have near-equal degree -> no divergence tail. 4-edge named-register pipeline.
// Stat epilogue: block's 32 rows in LDS; wave w does MFMA tile (w>>1), col-half (w&1).
template <int MODE>
__global__ __launch_bounds__(256) void csr_aggr_k(const int* __restrict__ rowstart,
                                                  const int* __restrict__ epack,
                                                  const float* __restrict__ bond,
                                                  const unsigned short* __restrict__ A,
                                                  const float* __restrict__ stat2prev,
                                                  const float* __restrict__ g,
                                                  const float* __restrict__ be,
                                                  const unsigned short* __restrict__ Wt1,
                                                  const int* __restrict__ perm,
                                                  unsigned short* __restrict__ B,
                                                  float* __restrict__ stat1) {
  __shared__ float bl[5][68];   // bond, padded rows
  __shared__ float scl64[64], shf64[64];
  __shared__ unsigned short Bs[32][72];   // block's B tile for stat MFMA
  int tid = threadIdx.x;
  for (int j = tid; j < 320; j += 256) bl[j >> 6][j & 63] = bond[j];
  if (MODE && tid < 64) {
    float s = 0.f, s2 = 0.f;
#pragma unroll
    for (int r = 0; r < NSTRIPE; ++r) {
      s += stat2prev[r * 128 + tid];
      s2 += stat2prev[r * 128 + 64 + tid];
    }
    float mean = s * (1.f / NN);
    float var = fmaxf(s2 * (1.f / NN) - mean * mean, 0.f);
    float sc = g[tid] * rsqrtf(var + EPS);
    scl64[tid] = sc;
    shf64[tid] = be[tid] - mean * sc;
  }
  __syncthreads();

  int lane = tid & 63;
  int sg = lane >> 3, ch = lane & 7, c0 = ch * 8;
  int rloc = (tid >> 6) * 8 + sg;                 // 0..31 within block
  int row = perm[blockIdx.x * 32 + rloc];         // degree-sorted row id
  float sc[8], sf[8];
  if (MODE) {
#pragma unroll
    for (int j = 0; j < 8; ++j) { sc[j] = scl64[c0 + j]; sf[j] = shf64[c0 + j]; }
  }
  int s = rowstart[row], e = rowstart[row + 1];
  float acc[8];
#pragma unroll
  for (int j = 0; j < 8; ++j) acc[j] = 0.f;
  int i = s;
  for (; i + 4 <= e; i += 4) {
    int p0 = epack[i], p1 = epack[i + 1], p2 = epack[i + 2], p3 = epack[i + 3];
    union { bf16x8 b; unsigned short u[8]; } h0, h1, h2, h3;
    h0.b = *(const bf16x8*)(A + (size_t)(p0 >> 3) * 64 + c0);
    h1.b = *(const bf16x8*)(A + (size_t)(p1 >> 3) * 64 + c0);
    h2.b = *(const bf16x8*)(A + (size_t)(p2 >> 3) * 64 + c0);
    h3.b = *(const bf16x8*)(A + (size_t)(p3 >> 3) * 64 + c0);
    const float* bp0 = &bl[p0 & 7][c0];
    const float* bp1 = &bl[p1 & 7][c0];
    const float* bp2 = &bl[p2 & 7][c0];
    const float* bp3 = &bl[p3 & 7][c0];
    float4 x0 = *(const float4*)(bp0), x1 = *(const float4*)(bp0 + 4);
    float4 y0 = *(const float4*)(bp1), y1 = *(const float4*)(bp1 + 4);
    float4 z0 = *(const float4*)(bp2), z1 = *(const float4*)(bp2 + 4);
    float4 w0 = *(const float4*)(bp3), w1 = *(const float4*)(bp3 + 4);
    float b0[8] = {x0.x, x0.y, x0.z, x0.w, x1.x, x1.y, x1.z, x1.w};
    float b1[8] = {y0.x, y0.y, y0.z, y0.w, y1.x, y1.y, y1.z, y1.w};
    float b2v[8] = {z0.x, z0.y, z0.z, z0.w, z1.x, z1.y, z1.z, z1.w};
    float b3[8] = {w0.x, w0.y, w0.z, w0.w, w1.x, w1.y, w1.z, w1.w};
#pragma unroll
    for (int j = 0; j < 8; ++j) {
      float v0 = bf2f(h0.u[j]);
      float v1 = bf2f(h1.u[j]);
      float v2 = bf2f(h2.u[j]);
      float v3 = bf2f(h3.u[j]);
      if (MODE) {
        v0 = fmaxf(fmaf(v0, sc[j], sf[j]), 0.f);
        v1 = fmaxf(fmaf(v1, sc[j], sf[j]), 0.f);
        v2 = fmaxf(fmaf(v2, sc[j], sf[j]), 0.f);
        v3 = fmaxf(fmaf(v3, sc[j], sf[j]), 0.f);
      }
      acc[j] += fmaxf(v0 + b0[j], 0.f);
      acc[j] += fmaxf(v1 + b1[j], 0.f);
      acc[j] += fmaxf(v2 + b2v[j], 0.f);
      acc[j] += fmaxf(v3 + b3[j], 0.f);
    }
  }
  for (; i < e; ++i) {
    int p0 = epack[i];
    union { bf16x8 b; unsigned short u[8]; } h0;
    h0.b = *(const bf16x8*)(A + (size_t)(p0 >> 3) * 64 + c0);
    const float* bp0 = &bl[p0 & 7][c0];
    float4 x0 = *(const float4*)(bp0), x1 = *(const float4*)(bp0 + 4);
    float b0[8] = {x0.x, x0.y, x0.z, x0.w, x1.x, x1.y, x1.z, x1.w};
#pragma unroll
    for (int j = 0; j < 8; ++j) {
      float v0 = bf2f(h0.u[j]);
      if (MODE) v0 = fmaxf(fmaf(v0, sc[j], sf[j]), 0.f);
      acc[j] += fmaxf(v0 + b0[j], 0.f);
    }
  }
  union { bf16x8 b; unsigned short u[8]; } rv, o;
  rv.b = *(const bf16x8*)(A + (size_t)row * 64 + c0);
#pragma unroll
  for (int j = 0; j < 8; ++j) {
    float r = bf2f(rv.u[j]);
    if (MODE) r = fmaxf(fmaf(r, sc[j], sf[j]), 0.f);
    o.u[j] = f2bf(acc[j] + r);
  }
  *(bf16x8*)(B + (size_t)row * 64 + c0) = o.b;
  *(bf16x8*)&Bs[rloc][c0] = o.b;
  __syncthreads();

  // ---- stat epilogue: wave w -> 16-row tile (w>>1), 64-col half (w&1). Order-invariant. ----
  int w = tid >> 6;
  int rlo = lane & 15, khi = lane >> 4;
  int tile = w >> 1, gcol = (w & 1) * 64;
  bf16x8 fa0 = *(const bf16x8*)&Bs[tile * 16 + rlo][khi * 8];
  bf16x8 fa1 = *(const bf16x8*)&Bs[tile * 16 + rlo][khi * 8 + 32];
  float* dst = stat1 + (blockIdx.x & (NSTRIPE - 1)) * 256;
#pragma unroll
  for (int ct = 0; ct < 4; ++ct) {
    int c = gcol + ct * 16 + rlo;
    const bf16x8* bp = (const bf16x8*)(Wt1 + (size_t)c * 64 + khi * 8);
    f32x4 yacc;
    yacc[0] = 0.f; yacc[1] = 0.f; yacc[2] = 0.f; yacc[3] = 0.f;
    yacc = __builtin_amdgcn_mfma_f32_16x16x32_bf16(fa0, bp[0], yacc, 0, 0, 0);
    yacc = __builtin_amdgcn_mfma_f32_16x16x32_bf16(fa1, bp[4], yacc, 0, 0, 0);
    float ss = 0.f, ss2 = 0.f;
#pragma unroll
    for (int q = 0; q < 4; ++q) {
      ss += yacc[q];
      ss2 = fmaf(yacc[q], yacc[q], ss2);
    }
    ss += __shfl_xor(ss, 16);  ss += __shfl_xor(ss, 32);
    ss2 += __shfl_xor(ss2, 16); ss2 += __shfl_xor(ss2, 32);
    if (khi == 0) {
      atomicAdd(&dst[c], ss);
      atomicAdd(&dst[128 + c], ss2);
    }
  }
}

// ---------------- fused gemm1+BN1+relu+gemm2; BN1 finalize from stat1 in prologue ----------------
__global__ __launch_bounds__(256) void gemm12_k(const unsigned short* __restrict__ B,
                                                const unsigned short* __restrict__ Wt1,
                                                const unsigned short* __restrict__ Wt2,
                                                const float* __restrict__ stat1,
                                                const float* __restrict__ g1,
                                                const float* __restrict__ be1,
                                                const float* __restrict__ b2,
                                                unsigned short* __restrict__ z2b,
                                                float* __restrict__ stat2f) {
  __shared__ unsigned short Zs[64][136];   // z1 tile (bf16, post BN1+relu)
  __shared__ float sclS[128], shfS[128], sred[128];
  int tid = threadIdx.x;
  int w = tid >> 6, lane = tid & 63;
  int rlo = lane & 15, khi = lane >> 4;
  int row0 = blockIdx.x * 64 + w * 16;
  // issue B loads BEFORE the prologue barrier: no dependence on stat1
  const bf16x8* ap = (const bf16x8*)(B + (size_t)(row0 + rlo) * 64 + khi * 8);
  bf16x8 a0 = ap[0], a1 = ap[4];
  if (tid < 128) {
    float s = 0.f, s2 = 0.f;
#pragma unroll
    for (int r = 0; r < NSTRIPE; ++r) {
      s += stat1[r * 256 + tid];
      s2 += stat1[r * 256 + 128 + tid];
    }
    float mean = s * (1.f / NN);
    float var = fmaxf(s2 * (1.f / NN) - mean * mean, 0.f);
    float sc = g1[tid] * rsqrtf(var + EPS);
    sclS[tid] = sc;
    shfS[tid] = be1[tid] - mean * sc;
    sred[tid] = 0.f;
  }
  __syncthreads();
#pragma unroll
  for (int ct = 0; ct < 8; ++ct) {
    const bf16x8* bp = (const bf16x8*)(Wt1 + (size_t)(ct * 16 + rlo) * 64 + khi * 8);
    f32x4 acc;
    acc[0] = 0.f; acc[1] = 0.f; acc[2] = 0.f; acc[3] = 0.f;
    acc = __builtin_amdgcn_mfma_f32_16x16x32_bf16(a0, bp[0], acc, 0, 0, 0);
    acc = __builtin_amdgcn_mfma_f32_16x16x32_bf16(a1, bp[4], acc, 0, 0, 0);
    int c = ct * 16 + rlo;
    float sc = sclS[c], sf = shfS[c];
#pragma unroll
    for (int q = 0; q < 4; ++q)
      Zs[w * 16 + khi * 4 + q][c] = f2bf(fmaxf(fmaf(acc[q], sc, sf), 0.f));
  }
  bf16x8 af0 = *(const bf16x8*)&Zs[w * 16 + rlo][khi * 8];
  bf16x8 af1 = *(const bf16x8*)&Zs[w * 16 + rlo][32 + khi * 8];
  bf16x8 af2 = *(const bf16x8*)&Zs[w * 16 + rlo][64 + khi * 8];
  bf16x8 af3 = *(const bf16x8*)&Zs[w * 16 + rlo][96 + khi * 8];
  __syncthreads();   // all reads done before Zs reused as z2 staging
  f32x4 acc2[4];
#pragma unroll
  for (int ct = 0; ct < 4; ++ct) { acc2[ct][0] = 0.f; acc2[ct][1] = 0.f; acc2[ct][2] = 0.f; acc2[ct][3] = 0.f; }
#pragma unroll
  for (int ct = 0; ct < 4; ++ct) {
    const bf16x8* bp = (const bf16x8*)(Wt2 + (size_t)(ct * 16 + rlo) * 128 + khi * 8);
    acc2[ct] = __builtin_amdgcn_mfma_f32_16x16x32_bf16(af0, bp[0], acc2[ct], 0, 0, 0);
    acc2[ct] = __builtin_amdgcn_mfma_f32_16x16x32_bf16(af1, bp[4], acc2[ct], 0, 0, 0);
    acc2[ct] = __builtin_amdgcn_mfma_f32_16x16x32_bf16(af2, bp[8], acc2[ct], 0, 0, 0);
    acc2[ct] = __builtin_amdgcn_mfma_f32_16x16x32_bf16(af3, bp[12], acc2[ct], 0, 0, 0);
  }
  unsigned short (*Z2)[72] = (unsigned short(*)[72])Zs;
#pragma unroll
  for (int ct = 0; ct < 4; ++ct) {
    int c = ct * 16 + rlo;
    float bs = b2[c];
    float s = 0.f, s2 = 0.f;
#pragma unroll
    for (int q = 0; q < 4; ++q) {
      int brow = w * 16 + khi * 4 + q;
      float v = acc2[ct][q] + bs;
      unsigned short ub = f2bf(v);
      Z2[brow][c] = ub;
      float vf = bf2f(ub);
      if (blockIdx.x * 64 + brow < NN) { s += vf; s2 += vf * vf; }
    }
    // reduce over khi lanes (same column c, different rows) -> 4x fewer LDS atomics
    s += __shfl_xor(s, 16);  s += __shfl_xor(s, 32);
    s2 += __shfl_xor(s2, 16); s2 += __shfl_xor(s2, 32);
    if (khi == 0) {
      atomicAdd(&sred[c], s);
      atomicAdd(&sred[64 + c], s2);
    }
  }
  __syncthreads();
#pragma unroll
  for (int pass = 0; pass < 2; ++pass) {
    int orow = pass * 32 + (tid >> 3), oc0 = (tid & 7) * 8;
    *(bf16x8*)(z2b + (size_t)(blockIdx.x * 64 + orow) * 64 + oc0) =
        *(const bf16x8*)&Z2[orow][oc0];
  }
  if (tid < 128)
    atomicAdd(&stat2f[(blockIdx.x & (NSTRIPE - 1)) * 128 + tid], sred[tid]);
}

// ---------------- fused final: BN2 apply (no relu) -> f32 h output + pool ----------------
__global__ __launch_bounds__(256) void final_k(const unsigned short* __restrict__ A,
                                               const float* __restrict__ stat2f,
                                               const float* __restrict__ g,
                                               const float* __restrict__ be,
                                               const int* __restrict__ batch,
                                               float* __restrict__ hf,
                                               float* __restrict__ xpool) {
  __shared__ float scl[64], shf[64];
  __shared__ float red[16][64];
  __shared__ int gfirst, gsame;
  int tid = threadIdx.x;
  if (tid < 64) {
    float s = 0.f, s2 = 0.f;
#pragma unroll
    for (int r = 0; r < NSTRIPE; ++r) {
      s += stat2f[r * 128 + tid];
      s2 += stat2f[r * 128 + 64 + tid];
    }
    float mean = s * (1.f / NN);
    float var = fmaxf(s2 * (1.f / NN) - mean * mean, 0.f);
    float sc = g[tid] * rsqrtf(var + EPS);
    scl[tid] = sc;
    shf[tid] = be[tid] - mean * sc;
  }
  int n0 = blockIdx.x * 16;   // 6250 blocks * 16 rows == NN
  if (tid == 0) {
    gfirst = batch[n0];
    gsame = (batch[n0] == batch[n0 + 15]) ? 1 : 0;
  }
  __syncthreads();
  int r = tid >> 4, c4 = tid & 15;
  int n = n0 + r;
  ushort4 raw = *(const ushort4*)(A + (size_t)n * 64 + c4 * 4);
  int cb = c4 * 4;
  float4 v;
  v.x = fmaf(bf2f(raw.x), scl[cb + 0], shf[cb + 0]);
  v.y = fmaf(bf2f(raw.y), scl[cb + 1], shf[cb + 1]);
  v.z = fmaf(bf2f(raw.z), scl[cb + 2], shf[cb + 2]);
  v.w = fmaf(bf2f(raw.w), scl[cb + 3], shf[cb + 3]);
  *(float4*)(hf + (size_t)n * 64 + cb) = v;
  *(float4*)&red[r][cb] = v;
  __syncthreads();
  if (gsame) {
#pragma unroll
    for (int off = 8; off >= 1; off >>= 1) {
      if (r < off) {
        float4 a = *(float4*)&red[r][cb];
        float4 b = *(float4*)&red[r + off][cb];
        *(float4*)&red[r][cb] = make_float4(a.x + b.x, a.y + b.y, a.z + b.z, a.w + b.w);
      }
      __syncthreads();
    }
    if (r == 0) {
      float* p = xpool + (size_t)gfirst * 64 + cb;
      float4 a = *(float4*)&red[0][cb];
      atomicAdd(p + 0, a.x); atomicAdd(p + 1, a.y);
      atomicAdd(p + 2, a.z); atomicAdd(p + 3, a.w);
    }
  } else {
    int gg = batch[n];
    float* p = xpool + (size_t)gg * 64 + cb;
    atomicAdd(p + 0, v.x); atomicAdd(p + 1, v.y);
    atomicAdd(p + 2, v.z); atomicAdd(p + 3, v.w);
  }
}

extern "C" void kernel_launch(void* const* d_in, const int* in_sizes, int n_in,
                              void* d_out, int out_size, void* d_ws, size_t ws_size,
                              hipStream_t stream) {
  const int* batch = (const int*)d_in[0];
  const int* x = (const int*)d_in[1];
  const int* ei = (const int*)d_in[2];
  const int* eattr = (const int*)d_in[3];
  const float* atom_emb = (const float*)d_in[4];
  const float* bond_emb = (const float*)d_in[5];
  const float* W1 = (const float*)d_in[6];
  const float* g1 = (const float*)d_in[8];
  const float* be1 = (const float*)d_in[9];
  const float* W2 = (const float*)d_in[10];
  const float* b2 = (const float*)d_in[11];
  const float* gbn = (const float*)d_in[12];
  const float* bbn = (const float*)d_in[13];

  float* out = (float*)d_out;
  float* xpool = out;               // 256*64
  float* hf = out + NG * 64;        // final f32 h lives directly in output

  char* ws = (char*)d_ws;
  unsigned short* A   = (unsigned short*)(ws);                      // NP*64 bf16 (h / z2)
  unsigned short* B   = (unsigned short*)(ws + 12804096);           // NP*64 bf16 (z = h+aggr)
  float* sbuf         = (float*)(ws + 25608192);                    // 5*12288 f32 = 245760 B
  unsigned short* Wt1 = (unsigned short*)(ws + 25853952);           // 5*128*64 bf16
  unsigned short* Wt2 = (unsigned short*)(ws + 25935872);           // 5*64*128 bf16
  int* rowstart       = (int*)(ws + 26017792);                      // NN+1 ints
  int* epack          = (int*)(ws + 26417796);                      // NE ints -> ends ~29.6MB
  int* perm           = (int*)(ws + 29617800);                      // NN ints (degree-sorted rows)
  // CSR build temporaries alias B region (dead until first csr_aggr)
  int* cnt    = (int*)(ws + 12804096);                              // NN ints + dhist(64) + dofs(64)
  int* dhist  = cnt + NN;
  int* dofs   = cnt + NN + 64;
  int* cursor = (int*)(ws + 12804096 + 1048576);
  int* bsum   = (int*)(ws + 12804096 + 2097152);

  prep_k<<<3837, 256, 0, stream>>>(x, atom_emb, A, W1, W2, Wt1, Wt2, cnt);

  // ---- CSR build (edge structure shared by all layers) ----
  hist_k<<<(NE + 255) / 256, 256, 0, stream>>>(ei, cnt);
  scan1_k<<<98, 256, 0, stream>>>(cnt, rowstart, bsum, dhist);
  dscan_k<<<1, 64, 0, stream>>>(dhist, dofs);
  scan3_k<<<(NN + 255) / 256, 256, 0, stream>>>(rowstart, bsum, cursor, cnt, dofs, perm);
  scatter_k<<<4 * ((NE + 255) / 256), 256, 0, stream>>>(ei, eattr, cursor, epack);

  hipMemsetAsync(sbuf, 0, 245760, stream);
  for (int l = 0; l < NL; ++l) {
    float* stat1 = sbuf + (size_t)l * 12288;            // [32][256]
    float* stat2 = sbuf + (size_t)l * 12288 + 8192;     // [32][128]
    float* stat2p = sbuf + (size_t)(l - 1) * 12288 + 8192;
    if (l == 0)
      csr_aggr_k<0><<<NN / 32, 256, 0, stream>>>(rowstart, epack, bond_emb, A,
                                                 sbuf, gbn, bbn,
                                                 Wt1, perm, B, stat1);
    else
      csr_aggr_k<1><<<NN / 32, 256, 0, stream>>>(rowstart, epack, bond_emb, A,
                                                 stat2p, gbn + (size_t)(l - 1) * 64,
                                                 bbn + (size_t)(l - 1) * 64,
                                                 Wt1 + (size_t)l * 128 * 64, perm, B, stat1);
    gemm12_k<<<NP / 64, 256, 0, stream>>>(B, Wt1 + (size_t)l * 128 * 64,
                                          Wt2 + (size_t)l * 64 * 128,
                                          stat1, g1 + (size_t)l * 128, be1 + (size_t)l * 128,
                                          b2 + (size_t)l * 64, A, stat2);
  }

  hipMemsetAsync(xpool, 0, (size_t)NG * 64 * 4, stream);
  final_k<<<NN / 16, 256, 0, stream>>>(A, sbuf + (size_t)(NL - 1) * 12288 + 8192,
                                       gbn + (size_t)(NL - 1) * 64,
                                       bbn + (size_t)(NL - 1) * 64, batch, hf, xpool);
}

// Round 15
// 486.711 us; speedup vs baseline: 1.6890x; 1.6890x over previous
//
#include <hip/hip_runtime.h>
#include <cstdint>
#include <cstddef>

#define NN 100000
#define NP 100032
#define NE 800000
#define NG 256
#define NL 5
#define EPS 1e-5f
#define NSTRIPE 32

typedef __bf16 bf16x8 __attribute__((ext_vector_type(8)));
typedef float f32x4 __attribute__((ext_vector_type(4)));

__device__ __forceinline__ float bf2f(unsigned short u) {
  union { unsigned int i; float f; } x; x.i = ((unsigned int)u) << 16; return x.f;
}
__device__ __forceinline__ unsigned short f2bf(float f) {
  union { float f; unsigned int i; } x; x.f = f;
  unsigned int r = x.i + 0x7fffu + ((x.i >> 16) & 1u);
  return (unsigned short)(r >> 16);
}

// ---------------- fused prep: A = bf16(atom_emb[x]) | weight transpose | cnt+dhist zero ----------------
__global__ __launch_bounds__(256) void prep_k(const int* __restrict__ x,
                                              const float* __restrict__ atom_emb,
                                              unsigned short* __restrict__ A,
                                              const float* __restrict__ W1,
                                              const float* __restrict__ W2,
                                              unsigned short* __restrict__ Wt1,
                                              unsigned short* __restrict__ Wt2,
                                              int* __restrict__ cnt) {
  int b = blockIdx.x, t = threadIdx.x;
  if (b < 3125) {                       // init h: NN*8 threads
    int i = b * 256 + t;
    int n = i >> 3, c0 = (i & 7) * 8;
    const float* p = atom_emb + (size_t)x[n] * 64 + c0;
    float4 v0 = *(const float4*)p;
    float4 v1 = *(const float4*)(p + 4);
    union { bf16x8 b8; unsigned short u[8]; } o;
    o.u[0] = f2bf(v0.x); o.u[1] = f2bf(v0.y); o.u[2] = f2bf(v0.z); o.u[3] = f2bf(v0.w);
    o.u[4] = f2bf(v1.x); o.u[5] = f2bf(v1.y); o.u[6] = f2bf(v1.z); o.u[7] = f2bf(v1.w);
    *(bf16x8*)(A + (size_t)n * 64 + c0) = o.b8;
  } else if (b < 3445) {                // wconv: 81920 threads (320 blocks exactly)
    int i = (b - 3125) * 256 + t;
    const int S = NL * 128 * 64;        // 40960
    if (i < S) {
      int l = i / (128 * 64), r = i % (128 * 64);
      int c = r / 64, k = r % 64;
      Wt1[i] = f2bf(W1[(size_t)l * 64 * 128 + (size_t)k * 128 + c]);
    } else {
      int j = i - S;
      int l = j / (128 * 64), r = j % (128 * 64);
      int c = r / 128, k = r % 128;
      Wt2[j] = f2bf(W2[(size_t)l * 128 * 64 + (size_t)k * 64 + c]);
    }
  } else {                              // zero cnt + dhist + dofs (NN+128 ints)
    int i = (b - 3445) * 256 + t;
    if (i < NN + 128) cnt[i] = 0;
  }
}

// ---------------- CSR build ----------------
__global__ __launch_bounds__(256) void hist_k(const int* __restrict__ ei,
                                              int* __restrict__ cnt) {
  int e = blockIdx.x * 256 + threadIdx.x;
  if (e >= NE) return;
  atomicAdd(&cnt[ei[NE + e]], 1);
}

// exclusive scan of cnt -> rs, block sums -> bsum; also degree histogram -> dhist
__global__ __launch_bounds__(256) void scan1_k(const int* __restrict__ cnt,
                                               int* __restrict__ rs,
                                               int* __restrict__ bsum,
                                               int* __restrict__ dhist) {
  __shared__ int sh[256];
  __shared__ int dh[64];
  int t = threadIdx.x;
  if (t < 64) dh[t] = 0;
  int base = blockIdx.x * 1024 + t * 4;
  int v0 = 0, v1 = 0, v2 = 0, v3 = 0;
  if (base + 0 < NN) v0 = cnt[base + 0];
  if (base + 1 < NN) v1 = cnt[base + 1];
  if (base + 2 < NN) v2 = cnt[base + 2];
  if (base + 3 < NN) v3 = cnt[base + 3];
  int tsum = v0 + v1 + v2 + v3;
  sh[t] = tsum;
  __syncthreads();
  if (base + 0 < NN) atomicAdd(&dh[v0 < 63 ? v0 : 63], 1);
  if (base + 1 < NN) atomicAdd(&dh[v1 < 63 ? v1 : 63], 1);
  if (base + 2 < NN) atomicAdd(&dh[v2 < 63 ? v2 : 63], 1);
  if (base + 3 < NN) atomicAdd(&dh[v3 < 63 ? v3 : 63], 1);
  for (int off = 1; off < 256; off <<= 1) {
    int x = (t >= off) ? sh[t - off] : 0;
    __syncthreads();
    sh[t] += x;
    __syncthreads();
  }
  int excl = sh[t] - tsum;
  if (base + 0 < NN) rs[base + 0] = excl;
  if (base + 1 < NN) rs[base + 1] = excl + v0;
  if (base + 2 < NN) rs[base + 2] = excl + v0 + v1;
  if (base + 3 < NN) rs[base + 3] = excl + v0 + v1 + v2;
  if (t == 255) bsum[blockIdx.x] = sh[255];
  __syncthreads();
  if (t < 64 && dh[t]) atomicAdd(&dhist[t], dh[t]);
}

// tiny: exclusive prefix of 64-entry degree histogram -> dofs
__global__ void dscan_k(const int* __restrict__ dhist, int* __restrict__ dofs) {
  if (threadIdx.x == 0 && blockIdx.x == 0) {
    int run = 0;
    for (int d = 0; d < 64; ++d) { dofs[d] = run; run += dhist[d]; }
  }
}

// scan3: fold block-sum prefix; init cursor; two-level counting-sort perm scatter
// (LDS histogram -> 1 global atomic per (block,bin) -> local distribute)
__global__ __launch_bounds__(256) void scan3_k(int* __restrict__ rs,
                                               const int* __restrict__ bsum,
                                               int* __restrict__ cursor,
                                               const int* __restrict__ cnt,
                                               int* __restrict__ dofs,
                                               int* __restrict__ perm) {
  __shared__ int lh[64], lofs[64];
  int t = threadIdx.x;
  if (t < 64) lh[t] = 0;
  __syncthreads();
  int i = blockIdx.x * 256 + t;
  int chunk = blockIdx.x >> 2;
  int boff = 0;
  for (int j = 0; j < chunk; ++j) boff += bsum[j];
  int d = 63, myslot = 0;
  if (i < NN) {
    int v = rs[i] + boff;
    rs[i] = v;
    cursor[i] = v;
    d = cnt[i]; if (d > 63) d = 63;
    myslot = atomicAdd(&lh[d], 1);
  }
  __syncthreads();
  if (t < 64 && lh[t]) lofs[t] = atomicAdd(&dofs[t], lh[t]);
  __syncthreads();
  if (i < NN) perm[lofs[d] + myslot] = i;
  if (i == 0) rs[NN] = NE;
}

// banded scatter: 4 bands of 25000 rows; each pass's epack slice stays cache-local
__global__ __launch_bounds__(256) void scatter_k(const int* __restrict__ ei,
                                                 const int* __restrict__ eattr,
                                                 int* __restrict__ cursor,
                                                 int* __restrict__ epack) {
  int band = blockIdx.x & 3;
  int e = (blockIdx.x >> 2) * 256 + threadIdx.x;
  if (e >= NE) return;
  int d = ei[NE + e];
  if (d / 25000 != band) return;
  int slot = atomicAdd(&cursor[d], 1);
  epack[slot] = (ei[e] << 3) | eattr[e];
}

// ---------------- gather + fused stat1 (degree-sorted rows) ----------------
// B[row] = hsrc(row) + sum relu(hsrc(src)+bond[b]); hsrc = MODE ? relu(A*scl+shf) : A.
// Subgroup-per-row (sg 0-7 = row, ch 0-7 = channels); row = perm[...]: rows in a wave
// have near-equal degree -> no divergence tail. 4-edge named-register pipeline.
// Stat epilogue: block's 32 rows in LDS; wave w does MFMA tile (w>>1), col-half (w&1).
template <int MODE>
__global__ __launch_bounds__(256) void csr_aggr_k(const int* __restrict__ rowstart,
                                                  const int* __restrict__ epack,
                                                  const float* __restrict__ bond,
                                                  const unsigned short* __restrict__ A,
                                                  const float* __restrict__ stat2prev,
                                                  const float* __restrict__ g,
                                                  const float* __restrict__ be,
                                                  const unsigned short* __restrict__ Wt1,
                                                  const int* __restrict__ perm,
                                                  unsigned short* __restrict__ B,
                                                  float* __restrict__ stat1) {
  __shared__ float bl[5][68];   // bond, padded rows
  __shared__ float scl64[64], shf64[64];
  __shared__ unsigned short Bs[32][72];   // block's B tile for stat MFMA
  int tid = threadIdx.x;
  for (int j = tid; j < 320; j += 256) bl[j >> 6][j & 63] = bond[j];
  if (MODE && tid < 64) {
    float s = 0.f, s2 = 0.f;
#pragma unroll
    for (int r = 0; r < NSTRIPE; ++r) {
      s += stat2prev[r * 128 + tid];
      s2 += stat2prev[r * 128 + 64 + tid];
    }
    float mean = s * (1.f / NN);
    float var = fmaxf(s2 * (1.f / NN) - mean * mean, 0.f);
    float sc = g[tid] * rsqrtf(var + EPS);
    scl64[tid] = sc;
    shf64[tid] = be[tid] - mean * sc;
  }
  __syncthreads();

  int lane = tid & 63;
  int sg = lane >> 3, ch = lane & 7, c0 = ch * 8;
  int rloc = (tid >> 6) * 8 + sg;                 // 0..31 within block
  int row = perm[blockIdx.x * 32 + rloc];         // degree-sorted row id
  float sc[8], sf[8];
  if (MODE) {
#pragma unroll
    for (int j = 0; j < 8; ++j) { sc[j] = scl64[c0 + j]; sf[j] = shf64[c0 + j]; }
  }
  int s = rowstart[row], e = rowstart[row + 1];
  float acc[8];
#pragma unroll
  for (int j = 0; j < 8; ++j) acc[j] = 0.f;
  int i = s;
  for (; i + 4 <= e; i += 4) {
    int p0 = epack[i], p1 = epack[i + 1], p2 = epack[i + 2], p3 = epack[i + 3];
    union { bf16x8 b; unsigned short u[8]; } h0, h1, h2, h3;
    h0.b = *(const bf16x8*)(A + (size_t)(p0 >> 3) * 64 + c0);
    h1.b = *(const bf16x8*)(A + (size_t)(p1 >> 3) * 64 + c0);
    h2.b = *(const bf16x8*)(A + (size_t)(p2 >> 3) * 64 + c0);
    h3.b = *(const bf16x8*)(A + (size_t)(p3 >> 3) * 64 + c0);
    const float* bp0 = &bl[p0 & 7][c0];
    const float* bp1 = &bl[p1 & 7][c0];
    const float* bp2 = &bl[p2 & 7][c0];
    const float* bp3 = &bl[p3 & 7][c0];
    float4 x0 = *(const float4*)(bp0), x1 = *(const float4*)(bp0 + 4);
    float4 y0 = *(const float4*)(bp1), y1 = *(const float4*)(bp1 + 4);
    float4 z0 = *(const float4*)(bp2), z1 = *(const float4*)(bp2 + 4);
    float4 w0 = *(const float4*)(bp3), w1 = *(const float4*)(bp3 + 4);
    float b0[8] = {x0.x, x0.y, x0.z, x0.w, x1.x, x1.y, x1.z, x1.w};
    float b1[8] = {y0.x, y0.y, y0.z, y0.w, y1.x, y1.y, y1.z, y1.w};
    float b2v[8] = {z0.x, z0.y, z0.z, z0.w, z1.x, z1.y, z1.z, z1.w};
    float b3[8] = {w0.x, w0.y, w0.z, w0.w, w1.x, w1.y, w1.z, w1.w};
#pragma unroll
    for (int j = 0; j < 8; ++j) {
      float v0 = bf2f(h0.u[j]);
      float v1 = bf2f(h1.u[j]);
      float v2 = bf2f(h2.u[j]);
      float v3 = bf2f(h3.u[j]);
      if (MODE) {
        v0 = fmaxf(fmaf(v0, sc[j], sf[j]), 0.f);
        v1 = fmaxf(fmaf(v1, sc[j], sf[j]), 0.f);
        v2 = fmaxf(fmaf(v2, sc[j], sf[j]), 0.f);
        v3 = fmaxf(fmaf(v3, sc[j], sf[j]), 0.f);
      }
      acc[j] += fmaxf(v0 + b0[j], 0.f);
      acc[j] += fmaxf(v1 + b1[j], 0.f);
      acc[j] += fmaxf(v2 + b2v[j], 0.f);
      acc[j] += fmaxf(v3 + b3[j], 0.f);
    }
  }
  for (; i < e; ++i) {
    int p0 = epack[i];
    union { bf16x8 b; unsigned short u[8]; } h0;
    h0.b = *(const bf16x8*)(A + (size_t)(p0 >> 3) * 64 + c0);
    const float* bp0 = &bl[p0 & 7][c0];
    float4 x0 = *(const float4*)(bp0), x1 = *(const float4*)(bp0 + 4);
    float b0[8] = {x0.x, x0.y, x0.z, x0.w, x1.x, x1.y, x1.z, x1.w};
#pragma unroll
    for (int j = 0; j < 8; ++j) {
      float v0 = bf2f(h0.u[j]);
      if (MODE) v0 = fmaxf(fmaf(v0, sc[j], sf[j]), 0.f);
      acc[j] += fmaxf(v0 + b0[j], 0.f);
    }
  }
  union { bf16x8 b; unsigned short u[8]; } rv, o;
  rv.b = *(const bf16x8*)(A + (size_t)row * 64 + c0);
#pragma unroll
  for (int j = 0; j < 8; ++j) {
    float r = bf2f(rv.u[j]);
    if (MODE) r = fmaxf(fmaf(r, sc[j], sf[j]), 0.f);
    o.u[j] = f2bf(acc[j] + r);
  }
  *(bf16x8*)(B + (size_t)row * 64 + c0) = o.b;
  *(bf16x8*)&Bs[rloc][c0] = o.b;
  __syncthreads();

  // ---- stat epilogue: wave w -> 16-row tile (w>>1), 64-col half (w&1). Order-invariant. ----
  int w = tid >> 6;
  int rlo = lane & 15, khi = lane >> 4;
  int tile = w >> 1, gcol = (w & 1) * 64;
  bf16x8 fa0 = *(const bf16x8*)&Bs[tile * 16 + rlo][khi * 8];
  bf16x8 fa1 = *(const bf16x8*)&Bs[tile * 16 + rlo][khi * 8 + 32];
  float* dst = stat1 + (blockIdx.x & (NSTRIPE - 1)) * 256;
#pragma unroll
  for (int ct = 0; ct < 4; ++ct) {
    int c = gcol + ct * 16 + rlo;
    const bf16x8* bp = (const bf16x8*)(Wt1 + (size_t)c * 64 + khi * 8);
    f32x4 yacc;
    yacc[0] = 0.f; yacc[1] = 0.f; yacc[2] = 0.f; yacc[3] = 0.f;
    yacc = __builtin_amdgcn_mfma_f32_16x16x32_bf16(fa0, bp[0], yacc, 0, 0, 0);
    yacc = __builtin_amdgcn_mfma_f32_16x16x32_bf16(fa1, bp[4], yacc, 0, 0, 0);
    float ss = 0.f, ss2 = 0.f;
#pragma unroll
    for (int q = 0; q < 4; ++q) {
      ss += yacc[q];
      ss2 = fmaf(yacc[q], yacc[q], ss2);
    }
    ss += __shfl_xor(ss, 16);  ss += __shfl_xor(ss, 32);
    ss2 += __shfl_xor(ss2, 16); ss2 += __shfl_xor(ss2, 32);
    if (khi == 0) {
      atomicAdd(&dst[c], ss);
      atomicAdd(&dst[128 + c], ss2);
    }
  }
}

// ---------------- fused gemm1+BN1+relu+gemm2; BN1 finalize from stat1 in prologue ----------------
__global__ __launch_bounds__(256) void gemm12_k(const unsigned short* __restrict__ B,
                                                const unsigned short* __restrict__ Wt1,
                                                const unsigned short* __restrict__ Wt2,
                                                const float* __restrict__ stat1,
                                                const float* __restrict__ g1,
                                                const float* __restrict__ be1,
                                                const float* __restrict__ b2,
                                                unsigned short* __restrict__ z2b,
                                                float* __restrict__ stat2f) {
  __shared__ unsigned short Zs[64][136];   // z1 tile (bf16, post BN1+relu)
  __shared__ float sclS[128], shfS[128], sred[128];
  int tid = threadIdx.x;
  int w = tid >> 6, lane = tid & 63;
  int rlo = lane & 15, khi = lane >> 4;
  int row0 = blockIdx.x * 64 + w * 16;
  // issue B loads BEFORE the prologue barrier: no dependence on stat1
  const bf16x8* ap = (const bf16x8*)(B + (size_t)(row0 + rlo) * 64 + khi * 8);
  bf16x8 a0 = ap[0], a1 = ap[4];
  if (tid < 128) {
    float s = 0.f, s2 = 0.f;
#pragma unroll
    for (int r = 0; r < NSTRIPE; ++r) {
      s += stat1[r * 256 + tid];
      s2 += stat1[r * 256 + 128 + tid];
    }
    float mean = s * (1.f / NN);
    float var = fmaxf(s2 * (1.f / NN) - mean * mean, 0.f);
    float sc = g1[tid] * rsqrtf(var + EPS);
    sclS[tid] = sc;
    shfS[tid] = be1[tid] - mean * sc;
    sred[tid] = 0.f;
  }
  __syncthreads();
#pragma unroll
  for (int ct = 0; ct < 8; ++ct) {
    const bf16x8* bp = (const bf16x8*)(Wt1 + (size_t)(ct * 16 + rlo) * 64 + khi * 8);
    f32x4 acc;
    acc[0] = 0.f; acc[1] = 0.f; acc[2] = 0.f; acc[3] = 0.f;
    acc = __builtin_amdgcn_mfma_f32_16x16x32_bf16(a0, bp[0], acc, 0, 0, 0);
    acc = __builtin_amdgcn_mfma_f32_16x16x32_bf16(a1, bp[4], acc, 0, 0, 0);
    int c = ct * 16 + rlo;
    float sc = sclS[c], sf = shfS[c];
#pragma unroll
    for (int q = 0; q < 4; ++q)
      Zs[w * 16 + khi * 4 + q][c] = f2bf(fmaxf(fmaf(acc[q], sc, sf), 0.f));
  }
  bf16x8 af0 = *(const bf16x8*)&Zs[w * 16 + rlo][khi * 8];
  bf16x8 af1 = *(const bf16x8*)&Zs[w * 16 + rlo][32 + khi * 8];
  bf16x8 af2 = *(const bf16x8*)&Zs[w * 16 + rlo][64 + khi * 8];
  bf16x8 af3 = *(const bf16x8*)&Zs[w * 16 + rlo][96 + khi * 8];
  __syncthreads();   // all reads done before Zs reused as z2 staging
  f32x4 acc2[4];
#pragma unroll
  for (int ct = 0; ct < 4; ++ct) { acc2[ct][0] = 0.f; acc2[ct][1] = 0.f; acc2[ct][2] = 0.f; acc2[ct][3] = 0.f; }
#pragma unroll
  for (int ct = 0; ct < 4; ++ct) {
    const bf16x8* bp = (const bf16x8*)(Wt2 + (size_t)(ct * 16 + rlo) * 128 + khi * 8);
    acc2[ct] = __builtin_amdgcn_mfma_f32_16x16x32_bf16(af0, bp[0], acc2[ct], 0, 0, 0);
    acc2[ct] = __builtin_amdgcn_mfma_f32_16x16x32_bf16(af1, bp[4], acc2[ct], 0, 0, 0);
    acc2[ct] = __builtin_amdgcn_mfma_f32_16x16x32_bf16(af2, bp[8], acc2[ct], 0, 0, 0);
    acc2[ct] = __builtin_amdgcn_mfma_f32_16x16x32_bf16(af3, bp[12], acc2[ct], 0, 0, 0);
  }
  unsigned short (*Z2)[72] = (unsigned short(*)[72])Zs;
#pragma unroll
  for (int ct = 0; ct < 4; ++ct) {
    int c = ct * 16 + rlo;
    float bs = b2[c];
    float s = 0.f, s2 = 0.f;
#pragma unroll
    for (int q = 0; q < 4; ++q) {
      int brow = w * 16 + khi * 4 + q;
      float v = acc2[ct][q] + bs;
      unsigned short ub = f2bf(v);
      Z2[brow][c] = ub;
      float vf = bf2f(ub);
      if (blockIdx.x * 64 + brow < NN) { s += vf; s2 += vf * vf; }
    }
    // reduce over khi lanes (same column c, different rows) -> 4x fewer LDS atomics
    s += __shfl_xor(s, 16);  s += __shfl_xor(s, 32);
    s2 += __shfl_xor(s2, 16); s2 += __shfl_xor(s2, 32);
    if (khi == 0) {
      atomicAdd(&sred[c], s);
      atomicAdd(&sred[64 + c], s2);
    }
  }
  __syncthreads();
#pragma unroll
  for (int pass = 0; pass < 2; ++pass) {
    int orow = pass * 32 + (tid >> 3), oc0 = (tid & 7) * 8;
    *(bf16x8*)(z2b + (size_t)(blockIdx.x * 64 + orow) * 64 + oc0) =
        *(const bf16x8*)&Z2[orow][oc0];
  }
  if (tid < 128)
    atomicAdd(&stat2f[(blockIdx.x & (NSTRIPE - 1)) * 128 + tid], sred[tid]);
}

// ---------------- fused final: BN2 apply (no relu) -> f32 h output + pool ----------------
__global__ __launch_bounds__(256) void final_k(const unsigned short* __restrict__ A,
                                               const float* __restrict__ stat2f,
                                               const float* __restrict__ g,
                                               const float* __restrict__ be,
                                               const int* __restrict__ batch,
                                               float* __restrict__ hf,
                                               float* __restrict__ xpool) {
  __shared__ float scl[64], shf[64];
  __shared__ float red[16][64];
  __shared__ int gfirst, gsame;
  int tid = threadIdx.x;
  if (tid < 64) {
    float s = 0.f, s2 = 0.f;
#pragma unroll
    for (int r = 0; r < NSTRIPE; ++r) {
      s += stat2f[r * 128 + tid];
      s2 += stat2f[r * 128 + 64 + tid];
    }
    float mean = s * (1.f / NN);
    float var = fmaxf(s2 * (1.f / NN) - mean * mean, 0.f);
    float sc = g[tid] * rsqrtf(var + EPS);
    scl[tid] = sc;
    shf[tid] = be[tid] - mean * sc;
  }
  int n0 = blockIdx.x * 16;   // 6250 blocks * 16 rows == NN
  if (tid == 0) {
    gfirst = batch[n0];
    gsame = (batch[n0] == batch[n0 + 15]) ? 1 : 0;
  }
  __syncthreads();
  int r = tid >> 4, c4 = tid & 15;
  int n = n0 + r;
  ushort4 raw = *(const ushort4*)(A + (size_t)n * 64 + c4 * 4);
  int cb = c4 * 4;
  float4 v;
  v.x = fmaf(bf2f(raw.x), scl[cb + 0], shf[cb + 0]);
  v.y = fmaf(bf2f(raw.y), scl[cb + 1], shf[cb + 1]);
  v.z = fmaf(bf2f(raw.z), scl[cb + 2], shf[cb + 2]);
  v.w = fmaf(bf2f(raw.w), scl[cb + 3], shf[cb + 3]);
  *(float4*)(hf + (size_t)n * 64 + cb) = v;
  *(float4*)&red[r][cb] = v;
  __syncthreads();
  if (gsame) {
#pragma unroll
    for (int off = 8; off >= 1; off >>= 1) {
      if (r < off) {
        float4 a = *(float4*)&red[r][cb];
        float4 b = *(float4*)&red[r + off][cb];
        *(float4*)&red[r][cb] = make_float4(a.x + b.x, a.y + b.y, a.z + b.z, a.w + b.w);
      }
      __syncthreads();
    }
    if (r == 0) {
      float* p = xpool + (size_t)gfirst * 64 + cb;
      float4 a = *(float4*)&red[0][cb];
      atomicAdd(p + 0, a.x); atomicAdd(p + 1, a.y);
      atomicAdd(p + 2, a.z); atomicAdd(p + 3, a.w);
    }
  } else {
    int gg = batch[n];
    float* p = xpool + (size_t)gg * 64 + cb;
    atomicAdd(p + 0, v.x); atomicAdd(p + 1, v.y);
    atomicAdd(p + 2, v.z); atomicAdd(p + 3, v.w);
  }
}

extern "C" void kernel_launch(void* const* d_in, const int* in_sizes, int n_in,
                              void* d_out, int out_size, void* d_ws, size_t ws_size,
                              hipStream_t stream) {
  const int* batch = (const int*)d_in[0];
  const int* x = (const int*)d_in[1];
  const int* ei = (const int*)d_in[2];
  const int* eattr = (const int*)d_in[3];
  const float* atom_emb = (const float*)d_in[4];
  const float* bond_emb = (const float*)d_in[5];
  const float* W1 = (const float*)d_in[6];
  const float* g1 = (const float*)d_in[8];
  const float* be1 = (const float*)d_in[9];
  const float* W2 = (const float*)d_in[10];
  const float* b2 = (const float*)d_in[11];
  const float* gbn = (const float*)d_in[12];
  const float* bbn = (const float*)d_in[13];

  float* out = (float*)d_out;
  float* xpool = out;               // 256*64
  float* hf = out + NG * 64;        // final f32 h lives directly in output

  char* ws = (char*)d_ws;
  unsigned short* A   = (unsigned short*)(ws);                      // NP*64 bf16 (h / z2)
  unsigned short* B   = (unsigned short*)(ws + 12804096);           // NP*64 bf16 (z = h+aggr)
  float* sbuf         = (float*)(ws + 25608192);                    // 5*12288 f32 = 245760 B
  unsigned short* Wt1 = (unsigned short*)(ws + 25853952);           // 5*128*64 bf16
  unsigned short* Wt2 = (unsigned short*)(ws + 25935872);           // 5*64*128 bf16
  int* rowstart       = (int*)(ws + 26017792);                      // NN+1 ints
  int* epack          = (int*)(ws + 26417796);                      // NE ints -> ends ~29.6MB
  int* perm           = (int*)(ws + 29617800);                      // NN ints (degree-sorted rows)
  // CSR build temporaries alias B region (dead until first csr_aggr)
  int* cnt    = (int*)(ws + 12804096);                              // NN ints + dhist(64) + dofs(64)
  int* dhist  = cnt + NN;
  int* dofs   = cnt + NN + 64;
  int* cursor = (int*)(ws + 12804096 + 1048576);
  int* bsum   = (int*)(ws + 12804096 + 2097152);

  prep_k<<<3837, 256, 0, stream>>>(x, atom_emb, A, W1, W2, Wt1, Wt2, cnt);

  // ---- CSR build (edge structure shared by all layers) ----
  hist_k<<<(NE + 255) / 256, 256, 0, stream>>>(ei, cnt);
  scan1_k<<<98, 256, 0, stream>>>(cnt, rowstart, bsum, dhist);
  dscan_k<<<1, 64, 0, stream>>>(dhist, dofs);
  scan3_k<<<(NN + 255) / 256, 256, 0, stream>>>(rowstart, bsum, cursor, cnt, dofs, perm);
  scatter_k<<<4 * ((NE + 255) / 256), 256, 0, stream>>>(ei, eattr, cursor, epack);

  hipMemsetAsync(sbuf, 0, 245760, stream);
  for (int l = 0; l < NL; ++l) {
    float* stat1 = sbuf + (size_t)l * 12288;            // [32][256]
    float* stat2 = sbuf + (size_t)l * 12288 + 8192;     // [32][128]
    float* stat2p = sbuf + (size_t)(l - 1) * 12288 + 8192;
    if (l == 0)
      csr_aggr_k<0><<<NN / 32, 256, 0, stream>>>(rowstart, epack, bond_emb, A,
                                                 sbuf, gbn, bbn,
                                                 Wt1, perm, B, stat1);
    else
      csr_aggr_k<1><<<NN / 32, 256, 0, stream>>>(rowstart, epack, bond_emb, A,
                                                 stat2p, gbn + (size_t)(l - 1) * 64,
                                                 bbn + (size_t)(l - 1) * 64,
                                                 Wt1 + (size_t)l * 128 * 64, perm, B, stat1);
    gemm12_k<<<NP / 64, 256, 0, stream>>>(B, Wt1 + (size_t)l * 128 * 64,
                                          Wt2 + (size_t)l * 64 * 128,
                                          stat1, g1 + (size_t)l * 128, be1 + (size_t)l * 128,
                                          b2 + (size_t)l * 64, A, stat2);
  }

  hipMemsetAsync(xpool, 0, (size_t)NG * 64 * 4, stream);
  final_k<<<NN / 16, 256, 0, stream>>>(A, sbuf + (size_t)(NL - 1) * 12288 + 8192,
                                       gbn + (size_t)(NL - 1) * 64,
                                       bbn + (size_t)(NL - 1) * 64, batch, hf, xpool);
}

// Round 16
// 484.224 us; speedup vs baseline: 1.6977x; 1.0051x over previous
//
#include <hip/hip_runtime.h>
#include <cstdint>
#include <cstddef>

#define NN 100000
#define NP 100032
#define NE 800000
#define NG 256
#define NL 5
#define EPS 1e-5f
#define NSTRIPE 32

typedef __bf16 bf16x8 __attribute__((ext_vector_type(8)));
typedef float f32x4 __attribute__((ext_vector_type(4)));

__device__ __forceinline__ float bf2f(unsigned short u) {
  union { unsigned int i; float f; } x; x.i = ((unsigned int)u) << 16; return x.f;
}
__device__ __forceinline__ unsigned short f2bf(float f) {
  union { float f; unsigned int i; } x; x.f = f;
  unsigned int r = x.i + 0x7fffu + ((x.i >> 16) & 1u);
  return (unsigned short)(r >> 16);
}

// ---------------- fused prep: A = bf16(atom_emb[x]) | weight transpose | cnt+dhist zero ----------------
__global__ __launch_bounds__(256) void prep_k(const int* __restrict__ x,
                                              const float* __restrict__ atom_emb,
                                              unsigned short* __restrict__ A,
                                              const float* __restrict__ W1,
                                              const float* __restrict__ W2,
                                              unsigned short* __restrict__ Wt1,
                                              unsigned short* __restrict__ Wt2,
                                              int* __restrict__ cnt) {
  int b = blockIdx.x, t = threadIdx.x;
  if (b < 3125) {                       // init h: NN*8 threads
    int i = b * 256 + t;
    int n = i >> 3, c0 = (i & 7) * 8;
    const float* p = atom_emb + (size_t)x[n] * 64 + c0;
    float4 v0 = *(const float4*)p;
    float4 v1 = *(const float4*)(p + 4);
    union { bf16x8 b8; unsigned short u[8]; } o;
    o.u[0] = f2bf(v0.x); o.u[1] = f2bf(v0.y); o.u[2] = f2bf(v0.z); o.u[3] = f2bf(v0.w);
    o.u[4] = f2bf(v1.x); o.u[5] = f2bf(v1.y); o.u[6] = f2bf(v1.z); o.u[7] = f2bf(v1.w);
    *(bf16x8*)(A + (size_t)n * 64 + c0) = o.b8;
  } else if (b < 3445) {                // wconv: 81920 threads (320 blocks exactly)
    int i = (b - 3125) * 256 + t;
    const int S = NL * 128 * 64;        // 40960
    if (i < S) {
      int l = i / (128 * 64), r = i % (128 * 64);
      int c = r / 64, k = r % 64;
      Wt1[i] = f2bf(W1[(size_t)l * 64 * 128 + (size_t)k * 128 + c]);
    } else {
      int j = i - S;
      int l = j / (128 * 64), r = j % (128 * 64);
      int c = r / 128, k = r % 128;
      Wt2[j] = f2bf(W2[(size_t)l * 128 * 64 + (size_t)k * 64 + c]);
    }
  } else {                              // zero cnt + dhist + dofs (NN+128 ints)
    int i = (b - 3445) * 256 + t;
    if (i < NN + 128) cnt[i] = 0;
  }
}

// ---------------- CSR build ----------------
__global__ __launch_bounds__(256) void hist_k(const int* __restrict__ ei,
                                              int* __restrict__ cnt) {
  int e = blockIdx.x * 256 + threadIdx.x;
  if (e >= NE) return;
  atomicAdd(&cnt[ei[NE + e]], 1);
}

// exclusive scan of cnt -> rs, block sums -> bsum; also degree histogram -> dhist
__global__ __launch_bounds__(256) void scan1_k(const int* __restrict__ cnt,
                                               int* __restrict__ rs,
                                               int* __restrict__ bsum,
                                               int* __restrict__ dhist) {
  __shared__ int sh[256];
  __shared__ int dh[64];
  int t = threadIdx.x;
  if (t < 64) dh[t] = 0;
  int base = blockIdx.x * 1024 + t * 4;
  int v0 = 0, v1 = 0, v2 = 0, v3 = 0;
  if (base + 0 < NN) v0 = cnt[base + 0];
  if (base + 1 < NN) v1 = cnt[base + 1];
  if (base + 2 < NN) v2 = cnt[base + 2];
  if (base + 3 < NN) v3 = cnt[base + 3];
  int tsum = v0 + v1 + v2 + v3;
  sh[t] = tsum;
  __syncthreads();
  if (base + 0 < NN) atomicAdd(&dh[v0 < 63 ? v0 : 63], 1);
  if (base + 1 < NN) atomicAdd(&dh[v1 < 63 ? v1 : 63], 1);
  if (base + 2 < NN) atomicAdd(&dh[v2 < 63 ? v2 : 63], 1);
  if (base + 3 < NN) atomicAdd(&dh[v3 < 63 ? v3 : 63], 1);
  for (int off = 1; off < 256; off <<= 1) {
    int x = (t >= off) ? sh[t - off] : 0;
    __syncthreads();
    sh[t] += x;
    __syncthreads();
  }
  int excl = sh[t] - tsum;
  if (base + 0 < NN) rs[base + 0] = excl;
  if (base + 1 < NN) rs[base + 1] = excl + v0;
  if (base + 2 < NN) rs[base + 2] = excl + v0 + v1;
  if (base + 3 < NN) rs[base + 3] = excl + v0 + v1 + v2;
  if (t == 255) bsum[blockIdx.x] = sh[255];
  __syncthreads();
  if (t < 64 && dh[t]) atomicAdd(&dhist[t], dh[t]);
}

// tiny: exclusive prefix of 64-entry degree histogram -> dofs
__global__ void dscan_k(const int* __restrict__ dhist, int* __restrict__ dofs) {
  if (threadIdx.x == 0 && blockIdx.x == 0) {
    int run = 0;
    for (int d = 0; d < 64; ++d) { dofs[d] = run; run += dhist[d]; }
  }
}

// scan3: fold block-sum prefix; init cursor; two-level counting-sort perm scatter
__global__ __launch_bounds__(256) void scan3_k(int* __restrict__ rs,
                                               const int* __restrict__ bsum,
                                               int* __restrict__ cursor,
                                               const int* __restrict__ cnt,
                                               int* __restrict__ dofs,
                                               int* __restrict__ perm) {
  __shared__ int lh[64], lofs[64];
  int t = threadIdx.x;
  if (t < 64) lh[t] = 0;
  __syncthreads();
  int i = blockIdx.x * 256 + t;
  int chunk = blockIdx.x >> 2;
  int boff = 0;
  for (int j = 0; j < chunk; ++j) boff += bsum[j];
  int d = 63, myslot = 0;
  if (i < NN) {
    int v = rs[i] + boff;
    rs[i] = v;
    cursor[i] = v;
    d = cnt[i]; if (d > 63) d = 63;
    myslot = atomicAdd(&lh[d], 1);
  }
  __syncthreads();
  if (t < 64 && lh[t]) lofs[t] = atomicAdd(&dofs[t], lh[t]);
  __syncthreads();
  if (i < NN) perm[lofs[d] + myslot] = i;
  if (i == 0) rs[NN] = NE;
}

// banded scatter: 4 bands of 25000 rows; each pass's epack slice stays cache-local
__global__ __launch_bounds__(256) void scatter_k(const int* __restrict__ ei,
                                                 const int* __restrict__ eattr,
                                                 int* __restrict__ cursor,
                                                 int* __restrict__ epack) {
  int band = blockIdx.x & 3;
  int e = (blockIdx.x >> 2) * 256 + threadIdx.x;
  if (e >= NE) return;
  int d = ei[NE + e];
  if (d / 25000 != band) return;
  int slot = atomicAdd(&cursor[d], 1);
  epack[slot] = (ei[e] << 3) | eattr[e];
}

// ---------------- tiny finalize kernels: stripe-reduce once per layer ----------------
__global__ void fin1_k(const float* __restrict__ stat1,
                       const float* __restrict__ g, const float* __restrict__ be,
                       float* __restrict__ scl, float* __restrict__ shf) {
  int c = threadIdx.x;   // 128
  float s = 0.f, s2 = 0.f;
#pragma unroll
  for (int r = 0; r < NSTRIPE; ++r) { s += stat1[r * 256 + c]; s2 += stat1[r * 256 + 128 + c]; }
  float mean = s * (1.f / NN);
  float var = fmaxf(s2 * (1.f / NN) - mean * mean, 0.f);
  float sc = g[c] * rsqrtf(var + EPS);
  scl[c] = sc;
  shf[c] = be[c] - mean * sc;
}

__global__ void fin2_k(const float* __restrict__ stat2,
                       const float* __restrict__ g, const float* __restrict__ be,
                       float* __restrict__ scl, float* __restrict__ shf) {
  int c = threadIdx.x;   // 64
  float s = 0.f, s2 = 0.f;
#pragma unroll
  for (int r = 0; r < NSTRIPE; ++r) { s += stat2[r * 128 + c]; s2 += stat2[r * 128 + 64 + c]; }
  float mean = s * (1.f / NN);
  float var = fmaxf(s2 * (1.f / NN) - mean * mean, 0.f);
  float sc = g[c] * rsqrtf(var + EPS);
  scl[c] = sc;
  shf[c] = be[c] - mean * sc;
}

// ---------------- gather + fused stat1 (degree-sorted rows) ----------------
// B[row] = hsrc(row) + sum relu(hsrc(src)+bond[b]); hsrc = MODE ? relu(A*scl+shf) : A.
// Subgroup-per-row (sg 0-7 = row, ch 0-7 = channels); row = perm[...]. 4-edge pipeline.
// Stat epilogue: block's 32 rows in LDS; wave w does MFMA tile (w>>1), col-half (w&1).
template <int MODE>
__global__ __launch_bounds__(256) void csr_aggr_k(const int* __restrict__ rowstart,
                                                  const int* __restrict__ epack,
                                                  const float* __restrict__ bond,
                                                  const unsigned short* __restrict__ A,
                                                  const float* __restrict__ scl2b,
                                                  const float* __restrict__ shf2b,
                                                  const unsigned short* __restrict__ Wt1,
                                                  const int* __restrict__ perm,
                                                  unsigned short* __restrict__ B,
                                                  float* __restrict__ stat1) {
  __shared__ float bl[5][68];   // bond, padded rows
  __shared__ float scl64[64], shf64[64];
  __shared__ unsigned short Bs[32][72];   // block's B tile for stat MFMA
  int tid = threadIdx.x;
  for (int j = tid; j < 320; j += 256) bl[j >> 6][j & 63] = bond[j];
  if (MODE && tid < 64) {
    scl64[tid] = scl2b[tid];
    shf64[tid] = shf2b[tid];
  }
  __syncthreads();

  int lane = tid & 63;
  int sg = lane >> 3, ch = lane & 7, c0 = ch * 8;
  int rloc = (tid >> 6) * 8 + sg;                 // 0..31 within block
  int row = perm[blockIdx.x * 32 + rloc];         // degree-sorted row id
  float sc[8], sf[8];
  if (MODE) {
#pragma unroll
    for (int j = 0; j < 8; ++j) { sc[j] = scl64[c0 + j]; sf[j] = shf64[c0 + j]; }
  }
  int s = rowstart[row], e = rowstart[row + 1];
  float acc[8];
#pragma unroll
  for (int j = 0; j < 8; ++j) acc[j] = 0.f;
  int i = s;
  for (; i + 4 <= e; i += 4) {
    int p0 = epack[i], p1 = epack[i + 1], p2 = epack[i + 2], p3 = epack[i + 3];
    union { bf16x8 b; unsigned short u[8]; } h0, h1, h2, h3;
    h0.b = *(const bf16x8*)(A + (size_t)(p0 >> 3) * 64 + c0);
    h1.b = *(const bf16x8*)(A + (size_t)(p1 >> 3) * 64 + c0);
    h2.b = *(const bf16x8*)(A + (size_t)(p2 >> 3) * 64 + c0);
    h3.b = *(const bf16x8*)(A + (size_t)(p3 >> 3) * 64 + c0);
    const float* bp0 = &bl[p0 & 7][c0];
    const float* bp1 = &bl[p1 & 7][c0];
    const float* bp2 = &bl[p2 & 7][c0];
    const float* bp3 = &bl[p3 & 7][c0];
    float4 x0 = *(const float4*)(bp0), x1 = *(const float4*)(bp0 + 4);
    float4 y0 = *(const float4*)(bp1), y1 = *(const float4*)(bp1 + 4);
    float4 z0 = *(const float4*)(bp2), z1 = *(const float4*)(bp2 + 4);
    float4 w0 = *(const float4*)(bp3), w1 = *(const float4*)(bp3 + 4);
    float b0[8] = {x0.x, x0.y, x0.z, x0.w, x1.x, x1.y, x1.z, x1.w};
    float b1[8] = {y0.x, y0.y, y0.z, y0.w, y1.x, y1.y, y1.z, y1.w};
    float b2v[8] = {z0.x, z0.y, z0.z, z0.w, z1.x, z1.y, z1.z, z1.w};
    float b3[8] = {w0.x, w0.y, w0.z, w0.w, w1.x, w1.y, w1.z, w1.w};
#pragma unroll
    for (int j = 0; j < 8; ++j) {
      float v0 = bf2f(h0.u[j]);
      float v1 = bf2f(h1.u[j]);
      float v2 = bf2f(h2.u[j]);
      float v3 = bf2f(h3.u[j]);
      if (MODE) {
        v0 = fmaxf(fmaf(v0, sc[j], sf[j]), 0.f);
        v1 = fmaxf(fmaf(v1, sc[j], sf[j]), 0.f);
        v2 = fmaxf(fmaf(v2, sc[j], sf[j]), 0.f);
        v3 = fmaxf(fmaf(v3, sc[j], sf[j]), 0.f);
      }
      acc[j] += fmaxf(v0 + b0[j], 0.f);
      acc[j] += fmaxf(v1 + b1[j], 0.f);
      acc[j] += fmaxf(v2 + b2v[j], 0.f);
      acc[j] += fmaxf(v3 + b3[j], 0.f);
    }
  }
  for (; i < e; ++i) {
    int p0 = epack[i];
    union { bf16x8 b; unsigned short u[8]; } h0;
    h0.b = *(const bf16x8*)(A + (size_t)(p0 >> 3) * 64 + c0);
    const float* bp0 = &bl[p0 & 7][c0];
    float4 x0 = *(const float4*)(bp0), x1 = *(const float4*)(bp0 + 4);
    float b0[8] = {x0.x, x0.y, x0.z, x0.w, x1.x, x1.y, x1.z, x1.w};
#pragma unroll
    for (int j = 0; j < 8; ++j) {
      float v0 = bf2f(h0.u[j]);
      if (MODE) v0 = fmaxf(fmaf(v0, sc[j], sf[j]), 0.f);
      acc[j] += fmaxf(v0 + b0[j], 0.f);
    }
  }
  union { bf16x8 b; unsigned short u[8]; } rv, o;
  rv.b = *(const bf16x8*)(A + (size_t)row * 64 + c0);
#pragma unroll
  for (int j = 0; j < 8; ++j) {
    float r = bf2f(rv.u[j]);
    if (MODE) r = fmaxf(fmaf(r, sc[j], sf[j]), 0.f);
    o.u[j] = f2bf(acc[j] + r);
  }
  *(bf16x8*)(B + (size_t)row * 64 + c0) = o.b;
  *(bf16x8*)&Bs[rloc][c0] = o.b;
  __syncthreads();

  // ---- stat epilogue: wave w -> 16-row tile (w>>1), 64-col half (w&1). Order-invariant. ----
  int w = tid >> 6;
  int rlo = lane & 15, khi = lane >> 4;
  int tile = w >> 1, gcol = (w & 1) * 64;
  bf16x8 fa0 = *(const bf16x8*)&Bs[tile * 16 + rlo][khi * 8];
  bf16x8 fa1 = *(const bf16x8*)&Bs[tile * 16 + rlo][khi * 8 + 32];
  float* dst = stat1 + (blockIdx.x & (NSTRIPE - 1)) * 256;
#pragma unroll
  for (int ct = 0; ct < 4; ++ct) {
    int c = gcol + ct * 16 + rlo;
    const bf16x8* bp = (const bf16x8*)(Wt1 + (size_t)c * 64 + khi * 8);
    f32x4 yacc;
    yacc[0] = 0.f; yacc[1] = 0.f; yacc[2] = 0.f; yacc[3] = 0.f;
    yacc = __builtin_amdgcn_mfma_f32_16x16x32_bf16(fa0, bp[0], yacc, 0, 0, 0);
    yacc = __builtin_amdgcn_mfma_f32_16x16x32_bf16(fa1, bp[4], yacc, 0, 0, 0);
    float ss = 0.f, ss2 = 0.f;
#pragma unroll
    for (int q = 0; q < 4; ++q) {
      ss += yacc[q];
      ss2 = fmaf(yacc[q], yacc[q], ss2);
    }
    ss += __shfl_xor(ss, 16);  ss += __shfl_xor(ss, 32);
    ss2 += __shfl_xor(ss2, 16); ss2 += __shfl_xor(ss2, 32);
    if (khi == 0) {
      atomicAdd(&dst[c], ss);
      atomicAdd(&dst[128 + c], ss2);
    }
  }
}

// ---------------- fused gemm1+BN1+relu+gemm2; scl/shf precomputed by fin1 ----------------
__global__ __launch_bounds__(256) void gemm12_k(const unsigned short* __restrict__ B,
                                                const unsigned short* __restrict__ Wt1,
                                                const unsigned short* __restrict__ Wt2,
                                                const float* __restrict__ scl1b,
                                                const float* __restrict__ shf1b,
                                                const float* __restrict__ b2,
                                                unsigned short* __restrict__ z2b,
                                                float* __restrict__ stat2f) {
  __shared__ unsigned short Zs[64][136];   // z1 tile (bf16, post BN1+relu)
  __shared__ float sclS[128], shfS[128], sred[128];
  int tid = threadIdx.x;
  int w = tid >> 6, lane = tid & 63;
  int rlo = lane & 15, khi = lane >> 4;
  int row0 = blockIdx.x * 64 + w * 16;
  const bf16x8* ap = (const bf16x8*)(B + (size_t)(row0 + rlo) * 64 + khi * 8);
  bf16x8 a0 = ap[0], a1 = ap[4];
  if (tid < 128) {
    sclS[tid] = scl1b[tid];
    shfS[tid] = shf1b[tid];
    sred[tid] = 0.f;
  }
  __syncthreads();
#pragma unroll
  for (int ct = 0; ct < 8; ++ct) {
    const bf16x8* bp = (const bf16x8*)(Wt1 + (size_t)(ct * 16 + rlo) * 64 + khi * 8);
    f32x4 acc;
    acc[0] = 0.f; acc[1] = 0.f; acc[2] = 0.f; acc[3] = 0.f;
    acc = __builtin_amdgcn_mfma_f32_16x16x32_bf16(a0, bp[0], acc, 0, 0, 0);
    acc = __builtin_amdgcn_mfma_f32_16x16x32_bf16(a1, bp[4], acc, 0, 0, 0);
    int c = ct * 16 + rlo;
    float sc = sclS[c], sf = shfS[c];
#pragma unroll
    for (int q = 0; q < 4; ++q)
      Zs[w * 16 + khi * 4 + q][c] = f2bf(fmaxf(fmaf(acc[q], sc, sf), 0.f));
  }
  bf16x8 af0 = *(const bf16x8*)&Zs[w * 16 + rlo][khi * 8];
  bf16x8 af1 = *(const bf16x8*)&Zs[w * 16 + rlo][32 + khi * 8];
  bf16x8 af2 = *(const bf16x8*)&Zs[w * 16 + rlo][64 + khi * 8];
  bf16x8 af3 = *(const bf16x8*)&Zs[w * 16 + rlo][96 + khi * 8];
  __syncthreads();   // all reads done before Zs reused as z2 staging
  f32x4 acc2[4];
#pragma unroll
  for (int ct = 0; ct < 4; ++ct) { acc2[ct][0] = 0.f; acc2[ct][1] = 0.f; acc2[ct][2] = 0.f; acc2[ct][3] = 0.f; }
#pragma unroll
  for (int ct = 0; ct < 4; ++ct) {
    const bf16x8* bp = (const bf16x8*)(Wt2 + (size_t)(ct * 16 + rlo) * 128 + khi * 8);
    acc2[ct] = __builtin_amdgcn_mfma_f32_16x16x32_bf16(af0, bp[0], acc2[ct], 0, 0, 0);
    acc2[ct] = __builtin_amdgcn_mfma_f32_16x16x32_bf16(af1, bp[4], acc2[ct], 0, 0, 0);
    acc2[ct] = __builtin_amdgcn_mfma_f32_16x16x32_bf16(af2, bp[8], acc2[ct], 0, 0, 0);
    acc2[ct] = __builtin_amdgcn_mfma_f32_16x16x32_bf16(af3, bp[12], acc2[ct], 0, 0, 0);
  }
  unsigned short (*Z2)[72] = (unsigned short(*)[72])Zs;
#pragma unroll
  for (int ct = 0; ct < 4; ++ct) {
    int c = ct * 16 + rlo;
    float bs = b2[c];
    float s = 0.f, s2 = 0.f;
#pragma unroll
    for (int q = 0; q < 4; ++q) {
      int brow = w * 16 + khi * 4 + q;
      float v = acc2[ct][q] + bs;
      unsigned short ub = f2bf(v);
      Z2[brow][c] = ub;
      float vf = bf2f(ub);
      if (blockIdx.x * 64 + brow < NN) { s += vf; s2 += vf * vf; }
    }
    s += __shfl_xor(s, 16);  s += __shfl_xor(s, 32);
    s2 += __shfl_xor(s2, 16); s2 += __shfl_xor(s2, 32);
    if (khi == 0) {
      atomicAdd(&sred[c], s);
      atomicAdd(&sred[64 + c], s2);
    }
  }
  __syncthreads();
#pragma unroll
  for (int pass = 0; pass < 2; ++pass) {
    int orow = pass * 32 + (tid >> 3), oc0 = (tid & 7) * 8;
    *(bf16x8*)(z2b + (size_t)(blockIdx.x * 64 + orow) * 64 + oc0) =
        *(const bf16x8*)&Z2[orow][oc0];
  }
  if (tid < 128)
    atomicAdd(&stat2f[(blockIdx.x & (NSTRIPE - 1)) * 128 + tid], sred[tid]);
}

// ---------------- fused final: BN2 apply (no relu) -> f32 h output + pool ----------------
__global__ __launch_bounds__(256) void final_k(const unsigned short* __restrict__ A,
                                               const float* __restrict__ scl2b,
                                               const float* __restrict__ shf2b,
                                               const int* __restrict__ batch,
                                               float* __restrict__ hf,
                                               float* __restrict__ xpool) {
  __shared__ float scl[64], shf[64];
  __shared__ float red[16][64];
  __shared__ int gfirst, gsame;
  int tid = threadIdx.x;
  if (tid < 64) {
    scl[tid] = scl2b[tid];
    shf[tid] = shf2b[tid];
  }
  int n0 = blockIdx.x * 16;   // 6250 blocks * 16 rows == NN
  if (tid == 0) {
    gfirst = batch[n0];
    gsame = (batch[n0] == batch[n0 + 15]) ? 1 : 0;
  }
  __syncthreads();
  int r = tid >> 4, c4 = tid & 15;
  int n = n0 + r;
  ushort4 raw = *(const ushort4*)(A + (size_t)n * 64 + c4 * 4);
  int cb = c4 * 4;
  float4 v;
  v.x = fmaf(bf2f(raw.x), scl[cb + 0], shf[cb + 0]);
  v.y = fmaf(bf2f(raw.y), scl[cb + 1], shf[cb + 1]);
  v.z = fmaf(bf2f(raw.z), scl[cb + 2], shf[cb + 2]);
  v.w = fmaf(bf2f(raw.w), scl[cb + 3], shf[cb + 3]);
  *(float4*)(hf + (size_t)n * 64 + cb) = v;
  *(float4*)&red[r][cb] = v;
  __syncthreads();
  if (gsame) {
#pragma unroll
    for (int off = 8; off >= 1; off >>= 1) {
      if (r < off) {
        float4 a = *(float4*)&red[r][cb];
        float4 b = *(float4*)&red[r + off][cb];
        *(float4*)&red[r][cb] = make_float4(a.x + b.x, a.y + b.y, a.z + b.z, a.w + b.w);
      }
      __syncthreads();
    }
    if (r == 0) {
      float* p = xpool + (size_t)gfirst * 64 + cb;
      float4 a = *(float4*)&red[0][cb];
      atomicAdd(p + 0, a.x); atomicAdd(p + 1, a.y);
      atomicAdd(p + 2, a.z); atomicAdd(p + 3, a.w);
    }
  } else {
    int gg = batch[n];
    float* p = xpool + (size_t)gg * 64 + cb;
    atomicAdd(p + 0, v.x); atomicAdd(p + 1, v.y);
    atomicAdd(p + 2, v.z); atomicAdd(p + 3, v.w);
  }
}

extern "C" void kernel_launch(void* const* d_in, const int* in_sizes, int n_in,
                              void* d_out, int out_size, void* d_ws, size_t ws_size,
                              hipStream_t stream) {
  const int* batch = (const int*)d_in[0];
  const int* x = (const int*)d_in[1];
  const int* ei = (const int*)d_in[2];
  const int* eattr = (const int*)d_in[3];
  const float* atom_emb = (const float*)d_in[4];
  const float* bond_emb = (const float*)d_in[5];
  const float* W1 = (const float*)d_in[6];
  const float* g1 = (const float*)d_in[8];
  const float* be1 = (const float*)d_in[9];
  const float* W2 = (const float*)d_in[10];
  const float* b2 = (const float*)d_in[11];
  const float* gbn = (const float*)d_in[12];
  const float* bbn = (const float*)d_in[13];

  float* out = (float*)d_out;
  float* xpool = out;               // 256*64
  float* hf = out + NG * 64;        // final f32 h lives directly in output

  char* ws = (char*)d_ws;
  unsigned short* A   = (unsigned short*)(ws);                      // NP*64 bf16 (h / z2)
  unsigned short* B   = (unsigned short*)(ws + 12804096);           // NP*64 bf16 (z = h+aggr)
  float* sbuf         = (float*)(ws + 25608192);                    // 5*12288 f32 = 245760 B
  unsigned short* Wt1 = (unsigned short*)(ws + 25853952);           // 5*128*64 bf16
  unsigned short* Wt2 = (unsigned short*)(ws + 25935872);           // 5*64*128 bf16
  int* rowstart       = (int*)(ws + 26017792);                      // NN+1 ints
  int* epack          = (int*)(ws + 26417796);                      // NE ints -> ends ~29.6MB
  int* perm           = (int*)(ws + 29617800);                      // NN ints (degree-sorted rows)
  float* ssb          = (float*)(ws + 30017800);                    // scl1(128)+shf1(128)+scl2(64)+shf2(64)
  float* scl1b = ssb, *shf1b = ssb + 128;
  float* scl2b = ssb + 256, *shf2b = ssb + 320;
  // CSR build temporaries alias B region (dead until first csr_aggr)
  int* cnt    = (int*)(ws + 12804096);                              // NN ints + dhist(64) + dofs(64)
  int* dhist  = cnt + NN;
  int* dofs   = cnt + NN + 64;
  int* cursor = (int*)(ws + 12804096 + 1048576);
  int* bsum   = (int*)(ws + 12804096 + 2097152);

  prep_k<<<3837, 256, 0, stream>>>(x, atom_emb, A, W1, W2, Wt1, Wt2, cnt);

  // ---- CSR build (edge structure shared by all layers) ----
  hist_k<<<(NE + 255) / 256, 256, 0, stream>>>(ei, cnt);
  scan1_k<<<98, 256, 0, stream>>>(cnt, rowstart, bsum, dhist);
  dscan_k<<<1, 64, 0, stream>>>(dhist, dofs);
  scan3_k<<<(NN + 255) / 256, 256, 0, stream>>>(rowstart, bsum, cursor, cnt, dofs, perm);
  scatter_k<<<4 * ((NE + 255) / 256), 256, 0, stream>>>(ei, eattr, cursor, epack);

  hipMemsetAsync(sbuf, 0, 245760, stream);
  for (int l = 0; l < NL; ++l) {
    float* stat1 = sbuf + (size_t)l * 12288;            // [32][256]
    float* stat2 = sbuf + (size_t)l * 12288 + 8192;     // [32][128]
    if (l == 0)
      csr_aggr_k<0><<<NN / 32, 256, 0, stream>>>(rowstart, epack, bond_emb, A,
                                                 scl2b, shf2b, Wt1, perm, B, stat1);
    else
      csr_aggr_k<1><<<NN / 32, 256, 0, stream>>>(rowstart, epack, bond_emb, A,
                                                 scl2b, shf2b,
                                                 Wt1 + (size_t)l * 128 * 64, perm, B, stat1);
    fin1_k<<<1, 128, 0, stream>>>(stat1, g1 + (size_t)l * 128, be1 + (size_t)l * 128,
                                  scl1b, shf1b);
    gemm12_k<<<NP / 64, 256, 0, stream>>>(B, Wt1 + (size_t)l * 128 * 64,
                                          Wt2 + (size_t)l * 64 * 128,
                                          scl1b, shf1b, b2 + (size_t)l * 64, A, stat2);
    fin2_k<<<1, 64, 0, stream>>>(stat2, gbn + (size_t)l * 64, bbn + (size_t)l * 64,
                                 scl2b, shf2b);
  }

  hipMemsetAsync(xpool, 0, (size_t)NG * 64 * 4, stream);
  final_k<<<NN / 16, 256, 0, stream>>>(A, scl2b, shf2b, batch, hf, xpool);
}